// Round 1
// 691.331 us; speedup vs baseline: 1.0466x; 1.0466x over previous
//
#include <hip/hip_runtime.h>
#include <hip/hip_bf16.h>
#include <stdint.h>

// R3: gemm_qkv + gemm_out rewritten to the 256x256 8-phase counted-vmcnt
// template (T2 swizzle + T3/T4 deep pipeline + T5 setprio). 512 thr, 8 waves
// (2Mx4N), BK=64, 128KB LDS double-buffer. B-frags register-resident per
// K-tile (frees B LDS region after phase 1 -> deep staging window).
// Schedule derivation (per-wave vmem queue, 2 loads/half-tile):
//   ph1 stage A1(t+1) | ph2 B0(t+2) vm(10) | ph3 B1(t+2) | ph4 A0(t+2) vm(8)
//   ph5 A1(t+2)       | ph6 B0(t+3) vm(10) | ph7 B1(t+3) | ph8 A0(t+3) vm(8)
// Every region is staged >=1 phase after its last reader's lgkmcnt(0)+barrier,
// and every read is covered by a prior counted vmcnt (incl. peeled last iter).

#define BT    32768   // B*T
#define CDIM  1024

using bf16 = __hip_bfloat16;
typedef short  short8   __attribute__((ext_vector_type(8)));
typedef short  short4_t __attribute__((ext_vector_type(4)));
typedef unsigned short ushort4_t __attribute__((ext_vector_type(4)));
typedef float  floatx4  __attribute__((ext_vector_type(4)));

__device__ __forceinline__ float bfbits2f(unsigned short u) {
    union { unsigned int i; float f; } c; c.i = ((unsigned int)u) << 16; return c.f;
}

__device__ __forceinline__ void gld_lds16(const void* g, void* lds) {
    __builtin_amdgcn_global_load_lds(
        (const __attribute__((address_space(1))) uint32_t*)g,
        (__attribute__((address_space(3))) uint32_t*)lds,
        16, 0, 0);
}

// ---------------------------------------------------------------- zero ctx
__global__ void zero_kernel(float* __restrict__ p) {
    p[(size_t)blockIdx.x * 256 + threadIdx.x] = 0.0f;
}

// ------------------------------------------------------------ fp32 -> bf16
__global__ void cvt_kernel(const float* __restrict__ x,
                           const float* __restrict__ Wq, const float* __restrict__ Wk,
                           const float* __restrict__ Wv, const float* __restrict__ Wp,
                           bf16* __restrict__ xb, bf16* __restrict__ Wb) {
    const int XF4 = (BT * CDIM) / 4;           // 8388608
    int i = blockIdx.x * 256 + threadIdx.x;
    const float* src; bf16* dst; int off;
    if (i < XF4) { src = x; dst = xb; off = i; }
    else {
        int i2 = i - XF4;
        int wi = i2 >> 18;                      // 262144 float4 per matrix
        off = i2 & 0x3FFFF;
        src = (wi == 0) ? Wq : (wi == 1) ? Wk : (wi == 2) ? Wv : Wp;
        dst = Wb + (size_t)wi * 1048576;
    }
    float4 f = ((const float4*)src)[off];
    union { bf16 h[4]; short4_t v; } u;
    u.h[0] = __float2bfloat16(f.x); u.h[1] = __float2bfloat16(f.y);
    u.h[2] = __float2bfloat16(f.z); u.h[3] = __float2bfloat16(f.w);
    *(short4_t*)(dst + (size_t)off * 4) = u.v;
}

// =================== 256x256 / BK=64 8-phase GEMM pipeline =================
// LDS tile layout (per A/B, per buf, per half): [128 rows][8 chunks of 8 bf16]
// with chunk' = chunk ^ (row&7)  (conflict-free ds_read_b128: 16 lanes of a
// quad hit 8 distinct 16B slots, 2-way = free). global_load_lds writes
// linearly; the inverse swizzle is applied to the per-lane GLOBAL address.

__device__ __forceinline__ short8 frag_ld(const bf16* hb, int r, int s4q) {
    return *(const short8*)(hb + r * 64 + (((s4q) ^ (r & 7)) << 3));
}

// stage one 128x64 half-tile: 2 x global_load_lds_dwordx4 per thread
__device__ __forceinline__ void stage_half(const bf16* g, bf16* l, int tid) {
    int ln = tid & 63, w = tid >> 6;
    int r = w * 8 + (ln >> 3);
    int c = ((ln & 7) ^ (ln >> 3)) << 3;        // pre-swizzled source chunk
    gld_lds16(g + (size_t)r * CDIM + c, l + w * 512);
    gld_lds16(g + (size_t)(r + 64) * CDIM + c, l + 4096 + w * 512);
}

#define MFMA16(a, b, c) __builtin_amdgcn_mfma_f32_16x16x32_bf16(a, b, c, 0, 0, 0)

__device__ __forceinline__ void pipe256(const bf16* __restrict__ Ab,
                                        const bf16* __restrict__ Bb,
                                        bf16* ldsA, bf16* ldsB,
                                        int tid, floatx4 acc[8][4]) {
    const int lane = tid & 63;
    const int wv = tid >> 6;
    const int quad = lane >> 4, l15 = lane & 15;
    const int wm = wv >> 2, wn = wv & 3;
    const int rA0 = wm * 64 + l15;              // + mm*32 + ii*16
    const int rB0 = (wn & 1) * 64 + l15;        // + j*16
    const bf16* ldsBh = ldsB + (wn >> 1) * 8192;  // wave's fixed B half
    short8 bfr[4][2];

#define STAGE_A(b, h, kt) stage_half(Ab + (size_t)((h) * 128) * CDIM + (kt) * 64, \
                                     ldsA + (b) * 16384 + (h) * 8192, tid)
#define STAGE_B(b, h, kt) stage_half(Bb + (size_t)((h) * 128) * CDIM + (kt) * 64, \
                                     ldsB + (b) * 16384 + (h) * 8192, tid)
#define VMW(n) asm volatile("s_waitcnt vmcnt(" #n ")" ::: "memory")
#define VM_NONE

#define QPHASE(BUF, QA, MM, LOADB, STG, VMC) do {                              \
    const bf16* aH_ = ldsA + (BUF) * 16384 + (QA) * 8192;                      \
    short8 a00_ = frag_ld(aH_, rA0 + (MM) * 32,      quad);                    \
    short8 a01_ = frag_ld(aH_, rA0 + (MM) * 32,      4 + quad);                \
    short8 a10_ = frag_ld(aH_, rA0 + (MM) * 32 + 16, quad);                    \
    short8 a11_ = frag_ld(aH_, rA0 + (MM) * 32 + 16, 4 + quad);                \
    if (LOADB) {                                                               \
        const bf16* bH_ = ldsBh + (BUF) * 16384;                               \
        _Pragma("unroll")                                                      \
        for (int j = 0; j < 4; ++j) {                                          \
            bfr[j][0] = frag_ld(bH_, rB0 + j * 16, quad);                      \
            bfr[j][1] = frag_ld(bH_, rB0 + j * 16, 4 + quad);                  \
        }                                                                      \
    }                                                                          \
    STG; VMC;                                                                  \
    __builtin_amdgcn_s_barrier();                                              \
    asm volatile("s_waitcnt lgkmcnt(0)" ::: "memory");                         \
    __builtin_amdgcn_s_setprio(1);                                             \
    _Pragma("unroll")                                                          \
    for (int j = 0; j < 4; ++j) {                                              \
        acc[(QA)*4+(MM)*2  ][j] = MFMA16(a00_, bfr[j][0], acc[(QA)*4+(MM)*2  ][j]); \
        acc[(QA)*4+(MM)*2  ][j] = MFMA16(a01_, bfr[j][1], acc[(QA)*4+(MM)*2  ][j]); \
        acc[(QA)*4+(MM)*2+1][j] = MFMA16(a10_, bfr[j][0], acc[(QA)*4+(MM)*2+1][j]); \
        acc[(QA)*4+(MM)*2+1][j] = MFMA16(a11_, bfr[j][1], acc[(QA)*4+(MM)*2+1][j]); \
    }                                                                          \
    __builtin_amdgcn_s_setprio(0);                                             \
    __builtin_amdgcn_s_barrier();                                              \
} while (0)

    // prologue: t0 fully + t1 {B0,B1,A0}; wait oldest 3 halves (t0 B0,B1,A0)
    STAGE_B(0, 0, 0); STAGE_B(0, 1, 0); STAGE_A(0, 0, 0); STAGE_A(0, 1, 0);
    STAGE_B(1, 0, 1); STAGE_B(1, 1, 1); STAGE_A(1, 0, 1);
    VMW(8);
    __builtin_amdgcn_s_barrier();

    #pragma unroll 1
    for (int i = 0; i < 7; ++i) {
        int t = 2 * i;
        QPHASE(0, 0, 0, 1, STAGE_A(1, 1, t + 1), VM_NONE);
        QPHASE(0, 0, 1, 0, STAGE_B(0, 0, t + 2), VMW(10));
        QPHASE(0, 1, 0, 0, STAGE_B(0, 1, t + 2), VM_NONE);
        QPHASE(0, 1, 1, 0, STAGE_A(0, 0, t + 2), VMW(8));
        QPHASE(1, 0, 0, 1, STAGE_A(0, 1, t + 2), VM_NONE);
        QPHASE(1, 0, 1, 0, STAGE_B(1, 0, t + 3), VMW(10));
        QPHASE(1, 1, 0, 0, STAGE_B(1, 1, t + 3), VM_NONE);
        QPHASE(1, 1, 1, 0, STAGE_A(1, 0, t + 3), VMW(8));
    }
    // peeled last iteration (t=14): only A1(15) left to stage; exact waits
    QPHASE(0, 0, 0, 1, STAGE_A(1, 1, 15), VM_NONE);
    QPHASE(0, 0, 1, 0, VM_NONE, VMW(8));
    QPHASE(0, 1, 0, 0, VM_NONE, VM_NONE);
    QPHASE(0, 1, 1, 0, VM_NONE, VMW(2));
    QPHASE(1, 0, 0, 1, VM_NONE, VM_NONE);
    QPHASE(1, 0, 1, 0, VM_NONE, VMW(0));
    QPHASE(1, 1, 0, 0, VM_NONE, VM_NONE);
    QPHASE(1, 1, 1, 0, VM_NONE, VM_NONE);

#undef QPHASE
#undef STAGE_A
#undef STAGE_B
}

// ----------------------------------------------------- QKV GEMM + softmax
__global__ __launch_bounds__(512, 2)
void gemm_qkv(const bf16* __restrict__ A, const bf16* __restrict__ Bw,
              const float* __restrict__ bq, const float* __restrict__ bk,
              const float* __restrict__ bv,
              bf16* __restrict__ qb, bf16* __restrict__ kb, bf16* __restrict__ vb) {
    __shared__ bf16 ldsA[32768];
    __shared__ bf16 ldsB[32768];
    int tid = threadIdx.x;
    int bid = blockIdx.x;
    int swz = (bid & 7) * 192 + (bid >> 3);    // XCD-chunked, 1536 % 8 == 0
    int bn = swz % 12, bm = swz / 12;          // bn-fastest: A-panel L2 reuse

    floatx4 acc[8][4] = {};
    pipe256(A + (size_t)bm * 256 * CDIM, Bw + (size_t)bn * 256 * CDIM,
            ldsA, ldsB, tid, acc);

    int lane = tid & 63, wv = tid >> 6, quad = lane >> 4, l15 = lane & 15;
    int wm = wv >> 2, wn = wv & 3;
    int n_abs = bn * 256 + wn * 64;            // wave's 64 cols = one head blk
    bf16* dst; const float* biasp; int ncol0; bool smax;
    if (n_abs < 1024)      { dst = qb; biasp = bq; ncol0 = n_abs;        smax = true;  }
    else if (n_abs < 2048) { dst = kb; biasp = bk; ncol0 = n_abs - 1024; smax = true;  }
    else                   { dst = vb; biasp = bv; ncol0 = n_abs - 2048; smax = false; }
    float bias4[4];
    #pragma unroll
    for (int j = 0; j < 4; ++j) bias4[j] = biasp[ncol0 + j * 16 + l15];
    size_t row0 = (size_t)bm * 256 + wm * 64;

    #pragma unroll
    for (int i = 0; i < 8; ++i) {
        #pragma unroll
        for (int r = 0; r < 4; ++r) {
            float vals[4];
            #pragma unroll
            for (int j = 0; j < 4; ++j) vals[j] = acc[i][j][r] + bias4[j];
            if (smax) {
                float mx = fmaxf(fmaxf(vals[0], vals[1]), fmaxf(vals[2], vals[3]));
                #pragma unroll
                for (int d = 1; d < 16; d <<= 1) mx = fmaxf(mx, __shfl_xor(mx, d));
                float s = 0.f;
                #pragma unroll
                for (int j = 0; j < 4; ++j) { vals[j] = __expf(vals[j] - mx); s += vals[j]; }
                #pragma unroll
                for (int d = 1; d < 16; d <<= 1) s += __shfl_xor(s, d);
                float rinv = 1.0f / s;
                #pragma unroll
                for (int j = 0; j < 4; ++j) vals[j] *= rinv;
            }
            size_t row = row0 + ((i >> 2) * 128) + ((i & 3) * 16) + quad * 4 + r;
            #pragma unroll
            for (int j = 0; j < 4; ++j)
                dst[row * 1024 + ncol0 + j * 16 + l15] = __float2bfloat16(vals[j]);
        }
    }
}

// --------------------------------------------- context = k^T v  (+ k_sum)
__global__ __launch_bounds__(256)
void ctx_kernel(const bf16* __restrict__ kbuf, const bf16* __restrict__ vbuf,
                float* __restrict__ ctx, float* __restrict__ ksum) {
    int bid = blockIdx.x;
    int head = bid >> 4, chunk = bid & 15;
    int b = head >> 4, h = head & 15;
    size_t rowbase = (size_t)b * 8192 + (size_t)chunk * 512;
    int coff = h * 64;
    __shared__ bf16 ks[64 * 64];
    __shared__ bf16 vs[64 * 64];
    int tid = threadIdx.x;
    int lrow = tid >> 2, lpart = tid & 3;
    int di = tid >> 4, ei = tid & 15;

    float acc[16];
    #pragma unroll
    for (int i = 0; i < 16; ++i) acc[i] = 0.f;
    float ksv[4] = {0.f, 0.f, 0.f, 0.f};

    size_t gbase = (rowbase + lrow) * 1024 + coff + lpart * 16;
    short8 pk0 = *(const short8*)(kbuf + gbase);
    short8 pk1 = *(const short8*)(kbuf + gbase + 8);
    short8 pv0 = *(const short8*)(vbuf + gbase);
    short8 pv1 = *(const short8*)(vbuf + gbase + 8);

    for (int st = 0; st < 8; ++st) {
        __syncthreads();
        *(short8*)&ks[lrow * 64 + lpart * 16]     = pk0;
        *(short8*)&ks[lrow * 64 + lpart * 16 + 8] = pk1;
        *(short8*)&vs[lrow * 64 + lpart * 16]     = pv0;
        *(short8*)&vs[lrow * 64 + lpart * 16 + 8] = pv1;
        __syncthreads();
        if (st < 7) {
            size_t g = gbase + (size_t)(st + 1) * 64 * 1024;
            pk0 = *(const short8*)(kbuf + g);
            pk1 = *(const short8*)(kbuf + g + 8);
            pv0 = *(const short8*)(vbuf + g);
            pv1 = *(const short8*)(vbuf + g + 8);
        }
        for (int t = 0; t < 64; ++t) {
            ushort4_t ku = *(const ushort4_t*)&ks[t * 64 + di * 4];
            ushort4_t vu = *(const ushort4_t*)&vs[t * 64 + ei * 4];
            float kd[4], ve[4];
            #pragma unroll
            for (int i = 0; i < 4; ++i) { kd[i] = bfbits2f(ku[i]); ve[i] = bfbits2f(vu[i]); }
            #pragma unroll
            for (int i = 0; i < 4; ++i)
                #pragma unroll
                for (int j = 0; j < 4; ++j)
                    acc[i * 4 + j] = fmaf(kd[i], ve[j], acc[i * 4 + j]);
            #pragma unroll
            for (int j = 0; j < 4; ++j) ksv[j] += kd[j];
        }
    }
    float* cptr = ctx + (size_t)head * 4096;
    #pragma unroll
    for (int i = 0; i < 4; ++i)
        #pragma unroll
        for (int j = 0; j < 4; ++j)
            atomicAdd(&cptr[(di * 4 + i) * 64 + ei * 4 + j], acc[i * 4 + j]);
    if (ei == 0) {
        #pragma unroll
        for (int j = 0; j < 4; ++j) atomicAdd(&ksum[head * 64 + di * 4 + j], ksv[j]);
    }
}

// --------------------------------- out_attn = q @ ctx * Dinv + q  (MFMA)
#define QS 72
__global__ __launch_bounds__(256)
void attn_kernel(const bf16* __restrict__ qbuf, const float* __restrict__ ctx,
                 const float* __restrict__ ksum, bf16* __restrict__ ab) {
    int bid = blockIdx.x;
    int head = bid >> 7, tb = bid & 127;
    int b = head >> 4, h = head & 15;
    size_t row0 = (size_t)b * 8192 + (size_t)tb * 64;
    int coff = h * 64;
    __shared__ bf16 qs[64 * QS];
    __shared__ bf16 cts[64 * QS];
    __shared__ float ksums[64];
    __shared__ float dinv[64];
    int tid = threadIdx.x, lane = tid & 63, wv = tid >> 6;

    {
        int lrow = tid >> 2, lpart = tid & 3;
        size_t g = (row0 + lrow) * 1024 + coff + lpart * 16;
        short8 q0 = *(const short8*)(qbuf + g);
        short8 q1 = *(const short8*)(qbuf + g + 8);
        *(short8*)&qs[lrow * QS + lpart * 16]     = q0;
        *(short8*)&qs[lrow * QS + lpart * 16 + 8] = q1;
    }
    {
        const float* cp = ctx + (size_t)head * 4096;
        #pragma unroll
        for (int it = 0; it < 4; ++it) {
            int fi = it * 256 + tid;
            int d = fi >> 4, e0 = (fi & 15) * 4;
            float4 f = ((const float4*)cp)[fi];
            cts[(e0 + 0) * QS + d] = __float2bfloat16(f.x);
            cts[(e0 + 1) * QS + d] = __float2bfloat16(f.y);
            cts[(e0 + 2) * QS + d] = __float2bfloat16(f.z);
            cts[(e0 + 3) * QS + d] = __float2bfloat16(f.w);
        }
    }
    if (tid < 64) ksums[tid] = ksum[head * 64 + tid];
    __syncthreads();

    {
        int t = tid >> 2, dg = tid & 3;
        float p = 0.f;
        #pragma unroll
        for (int j = 0; j < 16; ++j)
            p = fmaf(__bfloat162float(qs[t * QS + dg * 16 + j]), ksums[dg * 16 + j], p);
        p += __shfl_xor(p, 1);
        p += __shfl_xor(p, 2);
        if (dg == 0) dinv[t] = 1.0f / p;
    }
    __syncthreads();

    int quad = lane >> 4, l15 = lane & 15;
    int trow0 = wv * 16;
    short8 aF0 = *(const short8*)&qs[(trow0 + l15) * QS + quad * 8];
    short8 aF1 = *(const short8*)&qs[(trow0 + l15) * QS + 32 + quad * 8];
    floatx4 acc[4] = {};
    #pragma unroll
    for (int ni = 0; ni < 4; ++ni) {
        short8 b0 = *(const short8*)&cts[(ni * 16 + l15) * QS + quad * 8];
        short8 b1 = *(const short8*)&cts[(ni * 16 + l15) * QS + 32 + quad * 8];
        acc[ni] = __builtin_amdgcn_mfma_f32_16x16x32_bf16(aF0, b0, acc[ni], 0, 0, 0);
        acc[ni] = __builtin_amdgcn_mfma_f32_16x16x32_bf16(aF1, b1, acc[ni], 0, 0, 0);
    }
    float dv[4];
    #pragma unroll
    for (int r = 0; r < 4; ++r) dv[r] = dinv[trow0 + quad * 4 + r];
    #pragma unroll
    for (int ni = 0; ni < 4; ++ni) {
        #pragma unroll
        for (int r = 0; r < 4; ++r) {
            int row = trow0 + quad * 4 + r;
            int col = ni * 16 + l15;
            float val = acc[ni][r] * dv[r] + __bfloat162float(qs[row * QS + col]);
            ab[(row0 + row) * 1024 + coff + col] = __float2bfloat16(val);
        }
    }
}

// --------------------------------------------------- output GEMM (fp32 out)
__global__ __launch_bounds__(512, 2)
void gemm_out(const bf16* __restrict__ A, const bf16* __restrict__ Bw,
              const float* __restrict__ bp, float* __restrict__ outp) {
    __shared__ bf16 ldsA[32768];
    __shared__ bf16 ldsB[32768];
    int tid = threadIdx.x;
    int bid = blockIdx.x;
    int swz = (bid & 7) * 64 + (bid >> 3);     // 512 % 8 == 0
    int bn = swz & 3, bm = swz >> 2;

    floatx4 acc[8][4] = {};
    pipe256(A + (size_t)bm * 256 * CDIM, Bw + (size_t)bn * 256 * CDIM,
            ldsA, ldsB, tid, acc);

    int lane = tid & 63, wv = tid >> 6, quad = lane >> 4, l15 = lane & 15;
    int wm = wv >> 2, wn = wv & 3;
    int gcol0 = bn * 256 + wn * 64;
    float bias4[4];
    #pragma unroll
    for (int j = 0; j < 4; ++j) bias4[j] = bp[gcol0 + j * 16 + l15];
    size_t row0 = (size_t)bm * 256 + wm * 64;

    #pragma unroll
    for (int i = 0; i < 8; ++i) {
        #pragma unroll
        for (int r = 0; r < 4; ++r) {
            size_t row = row0 + ((i >> 2) * 128) + ((i & 3) * 16) + quad * 4 + r;
            #pragma unroll
            for (int j = 0; j < 4; ++j)
                outp[row * 1024 + gcol0 + j * 16 + l15] = acc[i][j][r] + bias4[j];
        }
    }
}

// ------------------------------------------------------------------ launch
extern "C" void kernel_launch(void* const* d_in, const int* in_sizes, int n_in,
                              void* d_out, int out_size, void* d_ws, size_t ws_size,
                              hipStream_t stream) {
    const float* x  = (const float*)d_in[0];
    const float* Wq = (const float*)d_in[1];
    const float* bq = (const float*)d_in[2];
    const float* Wk = (const float*)d_in[3];
    const float* bk = (const float*)d_in[4];
    const float* Wv = (const float*)d_in[5];
    const float* bv = (const float*)d_in[6];
    const float* Wp = (const float*)d_in[7];
    const float* bp = (const float*)d_in[8];
    float* outp = (float*)d_out;

    char* ws = (char*)d_ws;
    bf16*  xb   = (bf16*)(ws);                       // 64 MB
    bf16*  Wb   = (bf16*)(ws + 67108864);            // 8 MB (Wq,Wk,Wv,Wp rows)
    bf16*  qb   = (bf16*)(ws + 75497472);            // 64 MB
    bf16*  kb   = (bf16*)(ws + 142606336);           // 64 MB
    bf16*  vb   = (bf16*)(ws + 209715200);           // 64 MB
    float* ctx  = (float*)(ws + 276824064);          // 1 MB
    float* ksum = (float*)(ws + 277872640);          // 16 KB
    bf16*  ab   = (bf16*)(ws);                       // aliases xb (dead by then)

    zero_kernel<<<1040, 256, 0, stream>>>(ctx);
    cvt_kernel<<<36864, 256, 0, stream>>>(x, Wq, Wk, Wv, Wp, xb, Wb);
    gemm_qkv<<<1536, 512, 0, stream>>>(xb, Wb, bq, bk, bv, qb, kb, vb);
    ctx_kernel<<<1024, 256, 0, stream>>>(kb, vb, ctx, ksum);
    attn_kernel<<<8192, 256, 0, stream>>>(qb, ctx, ksum, ab);
    gemm_out<<<512, 512, 0, stream>>>(ab, Wb + (size_t)3072 * 1024, bp, outp);
}

// Round 4
// 646.667 us; speedup vs baseline: 1.1189x; 1.0691x over previous
//
#include <hip/hip_runtime.h>
#include <hip/hip_bf16.h>
#include <stdint.h>

// R6 = bisect: GEMMs reverted to the exact R3-validated 8-phase pipeline
// (non-persistent, HW-passed); ctx_kernel keeps the R4 MFMA rewrite with
// XOR-swizzled LDS transpose. Isolates which component killed the container
// in R4/R5 while banking the ctx win if it is safe.

#define BT    32768   // B*T
#define CDIM  1024

using bf16 = __hip_bfloat16;
typedef short  short8   __attribute__((ext_vector_type(8)));
typedef short  short4_t __attribute__((ext_vector_type(4)));
typedef unsigned short ushort4_t __attribute__((ext_vector_type(4)));
typedef float  floatx4  __attribute__((ext_vector_type(4)));

__device__ __forceinline__ float bfbits2f(unsigned short u) {
    union { unsigned int i; float f; } c; c.i = ((unsigned int)u) << 16; return c.f;
}

__device__ __forceinline__ void gld_lds16(const void* g, void* lds) {
    __builtin_amdgcn_global_load_lds(
        (const __attribute__((address_space(1))) uint32_t*)g,
        (__attribute__((address_space(3))) uint32_t*)lds,
        16, 0, 0);
}

// ---------------------------------------------------------------- zero ctx
__global__ void zero_kernel(float* __restrict__ p) {
    p[(size_t)blockIdx.x * 256 + threadIdx.x] = 0.0f;
}

// ------------------------------------------------------------ fp32 -> bf16
__global__ void cvt_kernel(const float* __restrict__ x,
                           const float* __restrict__ Wq, const float* __restrict__ Wk,
                           const float* __restrict__ Wv, const float* __restrict__ Wp,
                           bf16* __restrict__ xb, bf16* __restrict__ Wb) {
    const int XF4 = (BT * CDIM) / 4;           // 8388608
    int i = blockIdx.x * 256 + threadIdx.x;
    const float* src; bf16* dst; int off;
    if (i < XF4) { src = x; dst = xb; off = i; }
    else {
        int i2 = i - XF4;
        int wi = i2 >> 18;                      // 262144 float4 per matrix
        off = i2 & 0x3FFFF;
        src = (wi == 0) ? Wq : (wi == 1) ? Wk : (wi == 2) ? Wv : Wp;
        dst = Wb + (size_t)wi * 1048576;
    }
    float4 f = ((const float4*)src)[off];
    union { bf16 h[4]; short4_t v; } u;
    u.h[0] = __float2bfloat16(f.x); u.h[1] = __float2bfloat16(f.y);
    u.h[2] = __float2bfloat16(f.z); u.h[3] = __float2bfloat16(f.w);
    *(short4_t*)(dst + (size_t)off * 4) = u.v;
}

// =================== 256x256 / BK=64 8-phase GEMM pipeline (R3) ===========
// LDS tile layout (per A/B, per buf, per half): [128 rows][8 chunks of 8 bf16]
// with chunk' = chunk ^ (row&7). global_load_lds writes linearly; inverse
// swizzle applied to the per-lane GLOBAL address.

__device__ __forceinline__ short8 frag_ld(const bf16* hb, int r, int s4q) {
    return *(const short8*)(hb + r * 64 + (((s4q) ^ (r & 7)) << 3));
}

// stage one 128x64 half-tile: 2 x global_load_lds_dwordx4 per thread
__device__ __forceinline__ void stage_half(const bf16* g, bf16* l, int tid) {
    int ln = tid & 63, w = tid >> 6;
    int r = w * 8 + (ln >> 3);
    int c = ((ln & 7) ^ (ln >> 3)) << 3;        // pre-swizzled source chunk
    gld_lds16(g + (size_t)r * CDIM + c, l + w * 512);
    gld_lds16(g + (size_t)(r + 64) * CDIM + c, l + 4096 + w * 512);
}

#define MFMA16(a, b, c) __builtin_amdgcn_mfma_f32_16x16x32_bf16(a, b, c, 0, 0, 0)
#define VMW(n) asm volatile("s_waitcnt vmcnt(" #n ")" ::: "memory")
#define VM_NONE

__device__ __forceinline__ void pipe256(const bf16* __restrict__ Ab,
                                        const bf16* __restrict__ Bb,
                                        bf16* ldsA, bf16* ldsB,
                                        int tid, floatx4 acc[8][4]) {
    const int lane = tid & 63;
    const int wv = tid >> 6;
    const int quad = lane >> 4, l15 = lane & 15;
    const int wm = wv >> 2, wn = wv & 3;
    const int rA0 = wm * 64 + l15;              // + mm*32 + ii*16
    const int rB0 = (wn & 1) * 64 + l15;        // + j*16
    const bf16* ldsBh = ldsB + (wn >> 1) * 8192;  // wave's fixed B half
    short8 bfr[4][2];

#define STAGE_A(b, h, kt) stage_half(Ab + (size_t)((h) * 128) * CDIM + (kt) * 64, \
                                     ldsA + (b) * 16384 + (h) * 8192, tid)
#define STAGE_B(b, h, kt) stage_half(Bb + (size_t)((h) * 128) * CDIM + (kt) * 64, \
                                     ldsB + (b) * 16384 + (h) * 8192, tid)

#define QPHASE(BUF, QA, MM, LOADB, STG, VMC) do {                              \
    const bf16* aH_ = ldsA + (BUF) * 16384 + (QA) * 8192;                      \
    short8 a00_ = frag_ld(aH_, rA0 + (MM) * 32,      quad);                    \
    short8 a01_ = frag_ld(aH_, rA0 + (MM) * 32,      4 + quad);                \
    short8 a10_ = frag_ld(aH_, rA0 + (MM) * 32 + 16, quad);                    \
    short8 a11_ = frag_ld(aH_, rA0 + (MM) * 32 + 16, 4 + quad);                \
    if (LOADB) {                                                               \
        const bf16* bH_ = ldsBh + (BUF) * 16384;                               \
        _Pragma("unroll")                                                      \
        for (int j = 0; j < 4; ++j) {                                          \
            bfr[j][0] = frag_ld(bH_, rB0 + j * 16, quad);                      \
            bfr[j][1] = frag_ld(bH_, rB0 + j * 16, 4 + quad);                  \
        }                                                                      \
    }                                                                          \
    STG; VMC;                                                                  \
    __builtin_amdgcn_s_barrier();                                              \
    asm volatile("s_waitcnt lgkmcnt(0)" ::: "memory");                         \
    __builtin_amdgcn_s_setprio(1);                                             \
    _Pragma("unroll")                                                          \
    for (int j = 0; j < 4; ++j) {                                              \
        acc[(QA)*4+(MM)*2  ][j] = MFMA16(a00_, bfr[j][0], acc[(QA)*4+(MM)*2  ][j]); \
        acc[(QA)*4+(MM)*2  ][j] = MFMA16(a01_, bfr[j][1], acc[(QA)*4+(MM)*2  ][j]); \
        acc[(QA)*4+(MM)*2+1][j] = MFMA16(a10_, bfr[j][0], acc[(QA)*4+(MM)*2+1][j]); \
        acc[(QA)*4+(MM)*2+1][j] = MFMA16(a11_, bfr[j][1], acc[(QA)*4+(MM)*2+1][j]); \
    }                                                                          \
    __builtin_amdgcn_s_setprio(0);                                             \
    __builtin_amdgcn_s_barrier();                                              \
} while (0)

    // prologue: t0 fully + t1 {B0,B1,A0}; wait oldest 3 halves (t0 B0,B1,A0)
    STAGE_B(0, 0, 0); STAGE_B(0, 1, 0); STAGE_A(0, 0, 0); STAGE_A(0, 1, 0);
    STAGE_B(1, 0, 1); STAGE_B(1, 1, 1); STAGE_A(1, 0, 1);
    VMW(8);
    __builtin_amdgcn_s_barrier();

    #pragma unroll 1
    for (int i = 0; i < 7; ++i) {
        int t = 2 * i;
        QPHASE(0, 0, 0, 1, STAGE_A(1, 1, t + 1), VM_NONE);
        QPHASE(0, 0, 1, 0, STAGE_B(0, 0, t + 2), VMW(10));
        QPHASE(0, 1, 0, 0, STAGE_B(0, 1, t + 2), VM_NONE);
        QPHASE(0, 1, 1, 0, STAGE_A(0, 0, t + 2), VMW(8));
        QPHASE(1, 0, 0, 1, STAGE_A(0, 1, t + 2), VM_NONE);
        QPHASE(1, 0, 1, 0, STAGE_B(1, 0, t + 3), VMW(10));
        QPHASE(1, 1, 0, 0, STAGE_B(1, 1, t + 3), VM_NONE);
        QPHASE(1, 1, 1, 0, STAGE_A(1, 0, t + 3), VMW(8));
    }
    // peeled last iteration (t=14): only A1(15) left to stage; exact waits
    QPHASE(0, 0, 0, 1, STAGE_A(1, 1, 15), VM_NONE);
    QPHASE(0, 0, 1, 0, VM_NONE, VMW(8));
    QPHASE(0, 1, 0, 0, VM_NONE, VM_NONE);
    QPHASE(0, 1, 1, 0, VM_NONE, VMW(2));
    QPHASE(1, 0, 0, 1, VM_NONE, VM_NONE);
    QPHASE(1, 0, 1, 0, VM_NONE, VMW(0));
    QPHASE(1, 1, 0, 0, VM_NONE, VM_NONE);
    QPHASE(1, 1, 1, 0, VM_NONE, VM_NONE);

#undef QPHASE
#undef STAGE_A
#undef STAGE_B
}

// ----------------------------------------------------- QKV GEMM + softmax
__global__ __launch_bounds__(512, 2)
void gemm_qkv(const bf16* __restrict__ A, const bf16* __restrict__ Bw,
              const float* __restrict__ bq, const float* __restrict__ bk,
              const float* __restrict__ bv,
              bf16* __restrict__ qb, bf16* __restrict__ kb, bf16* __restrict__ vb) {
    __shared__ bf16 ldsA[32768];
    __shared__ bf16 ldsB[32768];
    int tid = threadIdx.x;
    int bid = blockIdx.x;
    int swz = (bid & 7) * 192 + (bid >> 3);    // XCD-chunked, 1536 % 8 == 0
    int bn = swz % 12, bm = swz / 12;          // bn-fastest: A-panel L2 reuse

    floatx4 acc[8][4] = {};
    pipe256(A + (size_t)bm * 256 * CDIM, Bw + (size_t)bn * 256 * CDIM,
            ldsA, ldsB, tid, acc);

    int lane = tid & 63, wv = tid >> 6, quad = lane >> 4, l15 = lane & 15;
    int wm = wv >> 2, wn = wv & 3;
    int n_abs = bn * 256 + wn * 64;            // wave's 64 cols = one head blk
    bf16* dst; const float* biasp; int ncol0; bool smax;
    if (n_abs < 1024)      { dst = qb; biasp = bq; ncol0 = n_abs;        smax = true;  }
    else if (n_abs < 2048) { dst = kb; biasp = bk; ncol0 = n_abs - 1024; smax = true;  }
    else                   { dst = vb; biasp = bv; ncol0 = n_abs - 2048; smax = false; }
    float bias4[4];
    #pragma unroll
    for (int j = 0; j < 4; ++j) bias4[j] = biasp[ncol0 + j * 16 + l15];
    size_t row0 = (size_t)bm * 256 + wm * 64;

    #pragma unroll
    for (int i = 0; i < 8; ++i) {
        #pragma unroll
        for (int r = 0; r < 4; ++r) {
            float vals[4];
            #pragma unroll
            for (int j = 0; j < 4; ++j) vals[j] = acc[i][j][r] + bias4[j];
            if (smax) {
                float mx = fmaxf(fmaxf(vals[0], vals[1]), fmaxf(vals[2], vals[3]));
                #pragma unroll
                for (int d = 1; d < 16; d <<= 1) mx = fmaxf(mx, __shfl_xor(mx, d));
                float s = 0.f;
                #pragma unroll
                for (int j = 0; j < 4; ++j) { vals[j] = __expf(vals[j] - mx); s += vals[j]; }
                #pragma unroll
                for (int d = 1; d < 16; d <<= 1) s += __shfl_xor(s, d);
                float rinv = 1.0f / s;
                #pragma unroll
                for (int j = 0; j < 4; ++j) vals[j] *= rinv;
            }
            size_t row = row0 + ((i >> 2) * 128) + ((i & 3) * 16) + quad * 4 + r;
            #pragma unroll
            for (int j = 0; j < 4; ++j)
                dst[row * 1024 + ncol0 + j * 16 + l15] = __float2bfloat16(vals[j]);
        }
    }
}

// --------------------------------------------------- output GEMM (fp32 out)
__global__ __launch_bounds__(512, 2)
void gemm_out(const bf16* __restrict__ A, const bf16* __restrict__ Bw,
              const float* __restrict__ bp, float* __restrict__ outp) {
    __shared__ bf16 ldsA[32768];
    __shared__ bf16 ldsB[32768];
    int tid = threadIdx.x;
    int bid = blockIdx.x;
    int swz = (bid & 7) * 64 + (bid >> 3);     // 512 % 8 == 0
    int bn = swz & 3, bm = swz >> 2;

    floatx4 acc[8][4] = {};
    pipe256(A + (size_t)bm * 256 * CDIM, Bw + (size_t)bn * 256 * CDIM,
            ldsA, ldsB, tid, acc);

    int lane = tid & 63, wv = tid >> 6, quad = lane >> 4, l15 = lane & 15;
    int wm = wv >> 2, wn = wv & 3;
    int gcol0 = bn * 256 + wn * 64;
    float bias4[4];
    #pragma unroll
    for (int j = 0; j < 4; ++j) bias4[j] = bp[gcol0 + j * 16 + l15];
    size_t row0 = (size_t)bm * 256 + wm * 64;

    #pragma unroll
    for (int i = 0; i < 8; ++i) {
        #pragma unroll
        for (int r = 0; r < 4; ++r) {
            size_t row = row0 + ((i >> 2) * 128) + ((i & 3) * 16) + quad * 4 + r;
            #pragma unroll
            for (int j = 0; j < 4; ++j)
                outp[row * 1024 + gcol0 + j * 16 + l15] = acc[i][j][r] + bias4[j];
        }
    }
}

// --------------------------------------------- context = k^T v  (+ k_sum)
// MFMA version: per 64-token subtile, stage k,v TRANSPOSED (kT[d][t]) into
// LDS with block-XOR swizzle: elem (d,t) at d*64 + (((t>>3)^(d&7)^(d>>3))<<3
// | (t&7)). Writes (vary d-coarse) and b128 frag reads (vary d-fine + t-blk)
// are both conflict-free. Then ctx[d][e] += MFMA(kT-row d, vT-row e).
__global__ __launch_bounds__(256)
void ctx_kernel(const bf16* __restrict__ kbuf, const bf16* __restrict__ vbuf,
                float* __restrict__ ctx, float* __restrict__ ksum) {
    int bid = blockIdx.x;
    int head = bid >> 4, chunk = bid & 15;
    int b = head >> 4, h = head & 15;
    size_t rowbase = (size_t)b * 8192 + (size_t)chunk * 512;
    int coff = h * 64;
    __shared__ unsigned short kT[4096];
    __shared__ unsigned short vT[4096];
    __shared__ float ksum_s[64];
    int tid = threadIdx.x, lane = tid & 63, wv = tid >> 6;
    int quad = lane >> 4, l15 = lane & 15;
    int c8 = tid & 7, trow = tid >> 3;          // trow 0..31; t = trow, trow+32
    if (tid < 64) ksum_s[tid] = 0.f;

    float kacc[8] = {0.f, 0.f, 0.f, 0.f, 0.f, 0.f, 0.f, 0.f};
    floatx4 acc4[4] = {};

    size_t g0 = (rowbase + trow) * 1024 + coff + c8 * 8;
    short8 pk0 = *(const short8*)(kbuf + g0);
    short8 pk1 = *(const short8*)(kbuf + g0 + 32 * 1024);
    short8 pv0 = *(const short8*)(vbuf + g0);
    short8 pv1 = *(const short8*)(vbuf + g0 + 32 * 1024);

    int tb0 = trow >> 3;                        // t-block of trow (0..3)
    for (int st = 0; st < 8; ++st) {
        __syncthreads();
        #pragma unroll
        for (int j = 0; j < 8; ++j) {
            int d = c8 * 8 + j;                 // d&7 == j, d>>3 == c8
            int base = d * 64 + (trow & 7);
            int sw0 = (tb0 ^ j ^ c8) << 3;
            int sw1 = ((tb0 + 4) ^ j ^ c8) << 3;
            unsigned short ku0 = (unsigned short)((short*)&pk0)[j];
            unsigned short ku1 = (unsigned short)((short*)&pk1)[j];
            kT[base + sw0] = ku0;
            kT[base + sw1] = ku1;
            vT[base + sw0] = (unsigned short)((short*)&pv0)[j];
            vT[base + sw1] = (unsigned short)((short*)&pv1)[j];
            kacc[j] += bfbits2f(ku0) + bfbits2f(ku1);
        }
        __syncthreads();
        if (st < 7) {
            size_t g = g0 + (size_t)(st + 1) * 64 * 1024;
            pk0 = *(const short8*)(kbuf + g);
            pk1 = *(const short8*)(kbuf + g + 32 * 1024);
            pv0 = *(const short8*)(vbuf + g);
            pv1 = *(const short8*)(vbuf + g + 32 * 1024);
        }
        #pragma unroll
        for (int ks = 0; ks < 2; ++ks) {
            int dA = wv * 16 + l15;
            int blkA = (ks * 4 + quad) ^ (dA & 7) ^ (dA >> 3);
            short8 aF = *(const short8*)&kT[dA * 64 + (blkA << 3)];
            #pragma unroll
            for (int n = 0; n < 4; ++n) {
                int eB = n * 16 + l15;
                int blkB = (ks * 4 + quad) ^ (eB & 7) ^ (eB >> 3);
                short8 bF = *(const short8*)&vT[eB * 64 + (blkB << 3)];
                acc4[n] = MFMA16(aF, bF, acc4[n]);
            }
        }
    }

    // ksum: reduce over lanes sharing c8 (strides 8,16,32), LDS-accumulate
    #pragma unroll
    for (int j = 0; j < 8; ++j) {
        float v = kacc[j];
        v += __shfl_xor(v, 8); v += __shfl_xor(v, 16); v += __shfl_xor(v, 32);
        if (lane < 8) atomicAdd(&ksum_s[lane * 8 + j], v);
    }
    float* cptr = ctx + (size_t)head * 4096;
    #pragma unroll
    for (int n = 0; n < 4; ++n)
        #pragma unroll
        for (int rr = 0; rr < 4; ++rr) {
            int d = wv * 16 + quad * 4 + rr;
            int e = n * 16 + l15;
            atomicAdd(&cptr[d * 64 + e], acc4[n][rr]);
        }
    __syncthreads();
    if (tid < 64) atomicAdd(&ksum[head * 64 + tid], ksum_s[tid]);
}

// --------------------------------- out_attn = q @ ctx * Dinv + q  (MFMA)
#define QS 72
__global__ __launch_bounds__(256)
void attn_kernel(const bf16* __restrict__ qbuf, const float* __restrict__ ctx,
                 const float* __restrict__ ksum, bf16* __restrict__ ab) {
    int bid = blockIdx.x;
    int head = bid >> 7, tb = bid & 127;
    int b = head >> 4, h = head & 15;
    size_t row0 = (size_t)b * 8192 + (size_t)tb * 64;
    int coff = h * 64;
    __shared__ bf16 qs[64 * QS];
    __shared__ bf16 cts[64 * QS];
    __shared__ float ksums[64];
    __shared__ float dinv[64];
    int tid = threadIdx.x, lane = tid & 63, wv = tid >> 6;

    {
        int lrow = tid >> 2, lpart = tid & 3;
        size_t g = (row0 + lrow) * 1024 + coff + lpart * 16;
        short8 q0 = *(const short8*)(qbuf + g);
        short8 q1 = *(const short8*)(qbuf + g + 8);
        *(short8*)&qs[lrow * QS + lpart * 16]     = q0;
        *(short8*)&qs[lrow * QS + lpart * 16 + 8] = q1;
    }
    {
        const float* cp = ctx + (size_t)head * 4096;
        #pragma unroll
        for (int it = 0; it < 4; ++it) {
            int fi = it * 256 + tid;
            int d = fi >> 4, e0 = (fi & 15) * 4;
            float4 f = ((const float4*)cp)[fi];
            cts[(e0 + 0) * QS + d] = __float2bfloat16(f.x);
            cts[(e0 + 1) * QS + d] = __float2bfloat16(f.y);
            cts[(e0 + 2) * QS + d] = __float2bfloat16(f.z);
            cts[(e0 + 3) * QS + d] = __float2bfloat16(f.w);
        }
    }
    if (tid < 64) ksums[tid] = ksum[head * 64 + tid];
    __syncthreads();

    {
        int t = tid >> 2, dg = tid & 3;
        float p = 0.f;
        #pragma unroll
        for (int j = 0; j < 16; ++j)
            p = fmaf(__bfloat162float(qs[t * QS + dg * 16 + j]), ksums[dg * 16 + j], p);
        p += __shfl_xor(p, 1);
        p += __shfl_xor(p, 2);
        if (dg == 0) dinv[t] = 1.0f / p;
    }
    __syncthreads();

    int quad = lane >> 4, l15 = lane & 15;
    int trow0 = wv * 16;
    short8 aF0 = *(const short8*)&qs[(trow0 + l15) * QS + quad * 8];
    short8 aF1 = *(const short8*)&qs[(trow0 + l15) * QS + 32 + quad * 8];
    floatx4 acc[4] = {};
    #pragma unroll
    for (int ni = 0; ni < 4; ++ni) {
        short8 b0 = *(const short8*)&cts[(ni * 16 + l15) * QS + quad * 8];
        short8 b1 = *(const short8*)&cts[(ni * 16 + l15) * QS + 32 + quad * 8];
        acc[ni] = __builtin_amdgcn_mfma_f32_16x16x32_bf16(aF0, b0, acc[ni], 0, 0, 0);
        acc[ni] = __builtin_amdgcn_mfma_f32_16x16x32_bf16(aF1, b1, acc[ni], 0, 0, 0);
    }
    float dv[4];
    #pragma unroll
    for (int r = 0; r < 4; ++r) dv[r] = dinv[trow0 + quad * 4 + r];
    #pragma unroll
    for (int ni = 0; ni < 4; ++ni) {
        #pragma unroll
        for (int r = 0; r < 4; ++r) {
            int row = trow0 + quad * 4 + r;
            int col = ni * 16 + l15;
            float val = acc[ni][r] * dv[r] + __bfloat162float(qs[row * QS + col]);
            ab[(row0 + row) * 1024 + coff + col] = __float2bfloat16(val);
        }
    }
}

// ------------------------------------------------------------------ launch
extern "C" void kernel_launch(void* const* d_in, const int* in_sizes, int n_in,
                              void* d_out, int out_size, void* d_ws, size_t ws_size,
                              hipStream_t stream) {
    const float* x  = (const float*)d_in[0];
    const float* Wq = (const float*)d_in[1];
    const float* bq = (const float*)d_in[2];
    const float* Wk = (const float*)d_in[3];
    const float* bk = (const float*)d_in[4];
    const float* Wv = (const float*)d_in[5];
    const float* bv = (const float*)d_in[6];
    const float* Wp = (const float*)d_in[7];
    const float* bp = (const float*)d_in[8];
    float* outp = (float*)d_out;

    char* ws = (char*)d_ws;
    bf16*  xb   = (bf16*)(ws);                       // 64 MB
    bf16*  Wb   = (bf16*)(ws + 67108864);            // 8 MB (Wq,Wk,Wv,Wp rows)
    bf16*  qb   = (bf16*)(ws + 75497472);            // 64 MB
    bf16*  kb   = (bf16*)(ws + 142606336);           // 64 MB
    bf16*  vb   = (bf16*)(ws + 209715200);           // 64 MB
    float* ctx  = (float*)(ws + 276824064);          // 1 MB
    float* ksum = (float*)(ws + 277872640);          // 16 KB
    bf16*  ab   = (bf16*)(ws);                       // aliases xb (dead by then)

    zero_kernel<<<1040, 256, 0, stream>>>(ctx);
    cvt_kernel<<<36864, 256, 0, stream>>>(x, Wq, Wk, Wv, Wp, xb, Wb);
    gemm_qkv<<<1536, 512, 0, stream>>>(xb, Wb, bq, bk, bv, qb, kb, vb);
    ctx_kernel<<<1024, 256, 0, stream>>>(kb, vb, ctx, ksum);
    attn_kernel<<<8192, 256, 0, stream>>>(qb, ctx, ksum, ab);
    gemm_out<<<512, 512, 0, stream>>>(ab, Wb + (size_t)3072 * 1024, bp, outp);
}

// Round 5
// 640.286 us; speedup vs baseline: 1.1301x; 1.0100x over previous
//
#include <hip/hip_runtime.h>
#include <hip/hip_bf16.h>
#include <stdint.h>

// R7 = R6 + low-risk slack removal: (1) attn_kernel processes 4 token-blocks
// per block (2048 blocks) with ctx staged once, double-buffered q LDS and
// register prefetch; (2) cvt grid-strided with zero folded in (prep_kernel,
// one fewer launch); (3) nontemporal stores for the final fp32 output.
// gemm_qkv/gemm_out/ctx_kernel pipelines byte-identical to R6 (HW-validated).

#define BT    32768   // B*T
#define CDIM  1024

using bf16 = __hip_bfloat16;
typedef short  short8   __attribute__((ext_vector_type(8)));
typedef short  short4_t __attribute__((ext_vector_type(4)));
typedef unsigned short ushort4_t __attribute__((ext_vector_type(4)));
typedef float  floatx4  __attribute__((ext_vector_type(4)));

__device__ __forceinline__ float bfbits2f(unsigned short u) {
    union { unsigned int i; float f; } c; c.i = ((unsigned int)u) << 16; return c.f;
}

__device__ __forceinline__ void gld_lds16(const void* g, void* lds) {
    __builtin_amdgcn_global_load_lds(
        (const __attribute__((address_space(1))) uint32_t*)g,
        (__attribute__((address_space(3))) uint32_t*)lds,
        16, 0, 0);
}

// ------------------------------------- fp32 -> bf16 conversion + ctx zeroing
__global__ __launch_bounds__(256)
void prep_kernel(const float* __restrict__ x,
                 const float* __restrict__ Wq, const float* __restrict__ Wk,
                 const float* __restrict__ Wv, const float* __restrict__ Wp,
                 bf16* __restrict__ xb, bf16* __restrict__ Wb,
                 float* __restrict__ zp) {
    const int XF4 = (BT * CDIM) / 4;           // 8388608
    const int TOT = XF4 + 4 * 262144;          // 9437184 = 9 * 1048576
    int t0 = blockIdx.x * 256 + threadIdx.x;   // grid 4096*256 = 1048576
    if (t0 < 66560) {                          // zero ctx (1MB) + ksum (16KB)
        float4 z = {0.f, 0.f, 0.f, 0.f};
        ((float4*)zp)[t0] = z;
    }
    #pragma unroll 1
    for (int i = t0; i < TOT; i += 1048576) {
        const float* src; bf16* dst; int off;
        if (i < XF4) { src = x; dst = xb; off = i; }
        else {
            int i2 = i - XF4;
            int wi = i2 >> 18;                  // 262144 float4 per matrix
            off = i2 & 0x3FFFF;
            src = (wi == 0) ? Wq : (wi == 1) ? Wk : (wi == 2) ? Wv : Wp;
            dst = Wb + (size_t)wi * 1048576;
        }
        float4 f = ((const float4*)src)[off];
        union { bf16 h[4]; short4_t v; } u;
        u.h[0] = __float2bfloat16(f.x); u.h[1] = __float2bfloat16(f.y);
        u.h[2] = __float2bfloat16(f.z); u.h[3] = __float2bfloat16(f.w);
        *(short4_t*)(dst + (size_t)off * 4) = u.v;
    }
}

// =================== 256x256 / BK=64 8-phase GEMM pipeline (R3) ===========
// LDS tile layout (per A/B, per buf, per half): [128 rows][8 chunks of 8 bf16]
// with chunk' = chunk ^ (row&7). global_load_lds writes linearly; inverse
// swizzle applied to the per-lane GLOBAL address.

__device__ __forceinline__ short8 frag_ld(const bf16* hb, int r, int s4q) {
    return *(const short8*)(hb + r * 64 + (((s4q) ^ (r & 7)) << 3));
}

// stage one 128x64 half-tile: 2 x global_load_lds_dwordx4 per thread
__device__ __forceinline__ void stage_half(const bf16* g, bf16* l, int tid) {
    int ln = tid & 63, w = tid >> 6;
    int r = w * 8 + (ln >> 3);
    int c = ((ln & 7) ^ (ln >> 3)) << 3;        // pre-swizzled source chunk
    gld_lds16(g + (size_t)r * CDIM + c, l + w * 512);
    gld_lds16(g + (size_t)(r + 64) * CDIM + c, l + 4096 + w * 512);
}

#define MFMA16(a, b, c) __builtin_amdgcn_mfma_f32_16x16x32_bf16(a, b, c, 0, 0, 0)
#define VMW(n) asm volatile("s_waitcnt vmcnt(" #n ")" ::: "memory")
#define VM_NONE

__device__ __forceinline__ void pipe256(const bf16* __restrict__ Ab,
                                        const bf16* __restrict__ Bb,
                                        bf16* ldsA, bf16* ldsB,
                                        int tid, floatx4 acc[8][4]) {
    const int lane = tid & 63;
    const int wv = tid >> 6;
    const int quad = lane >> 4, l15 = lane & 15;
    const int wm = wv >> 2, wn = wv & 3;
    const int rA0 = wm * 64 + l15;              // + mm*32 + ii*16
    const int rB0 = (wn & 1) * 64 + l15;        // + j*16
    const bf16* ldsBh = ldsB + (wn >> 1) * 8192;  // wave's fixed B half
    short8 bfr[4][2];

#define STAGE_A(b, h, kt) stage_half(Ab + (size_t)((h) * 128) * CDIM + (kt) * 64, \
                                     ldsA + (b) * 16384 + (h) * 8192, tid)
#define STAGE_B(b, h, kt) stage_half(Bb + (size_t)((h) * 128) * CDIM + (kt) * 64, \
                                     ldsB + (b) * 16384 + (h) * 8192, tid)

#define QPHASE(BUF, QA, MM, LOADB, STG, VMC) do {                              \
    const bf16* aH_ = ldsA + (BUF) * 16384 + (QA) * 8192;                      \
    short8 a00_ = frag_ld(aH_, rA0 + (MM) * 32,      quad);                    \
    short8 a01_ = frag_ld(aH_, rA0 + (MM) * 32,      4 + quad);                \
    short8 a10_ = frag_ld(aH_, rA0 + (MM) * 32 + 16, quad);                    \
    short8 a11_ = frag_ld(aH_, rA0 + (MM) * 32 + 16, 4 + quad);                \
    if (LOADB) {                                                               \
        const bf16* bH_ = ldsBh + (BUF) * 16384;                               \
        _Pragma("unroll")                                                      \
        for (int j = 0; j < 4; ++j) {                                          \
            bfr[j][0] = frag_ld(bH_, rB0 + j * 16, quad);                      \
            bfr[j][1] = frag_ld(bH_, rB0 + j * 16, 4 + quad);                  \
        }                                                                      \
    }                                                                          \
    STG; VMC;                                                                  \
    __builtin_amdgcn_s_barrier();                                              \
    asm volatile("s_waitcnt lgkmcnt(0)" ::: "memory");                         \
    __builtin_amdgcn_s_setprio(1);                                             \
    _Pragma("unroll")                                                          \
    for (int j = 0; j < 4; ++j) {                                              \
        acc[(QA)*4+(MM)*2  ][j] = MFMA16(a00_, bfr[j][0], acc[(QA)*4+(MM)*2  ][j]); \
        acc[(QA)*4+(MM)*2  ][j] = MFMA16(a01_, bfr[j][1], acc[(QA)*4+(MM)*2  ][j]); \
        acc[(QA)*4+(MM)*2+1][j] = MFMA16(a10_, bfr[j][0], acc[(QA)*4+(MM)*2+1][j]); \
        acc[(QA)*4+(MM)*2+1][j] = MFMA16(a11_, bfr[j][1], acc[(QA)*4+(MM)*2+1][j]); \
    }                                                                          \
    __builtin_amdgcn_s_setprio(0);                                             \
    __builtin_amdgcn_s_barrier();                                              \
} while (0)

    // prologue: t0 fully + t1 {B0,B1,A0}; wait oldest 3 halves (t0 B0,B1,A0)
    STAGE_B(0, 0, 0); STAGE_B(0, 1, 0); STAGE_A(0, 0, 0); STAGE_A(0, 1, 0);
    STAGE_B(1, 0, 1); STAGE_B(1, 1, 1); STAGE_A(1, 0, 1);
    VMW(8);
    __builtin_amdgcn_s_barrier();

    #pragma unroll 1
    for (int i = 0; i < 7; ++i) {
        int t = 2 * i;
        QPHASE(0, 0, 0, 1, STAGE_A(1, 1, t + 1), VM_NONE);
        QPHASE(0, 0, 1, 0, STAGE_B(0, 0, t + 2), VMW(10));
        QPHASE(0, 1, 0, 0, STAGE_B(0, 1, t + 2), VM_NONE);
        QPHASE(0, 1, 1, 0, STAGE_A(0, 0, t + 2), VMW(8));
        QPHASE(1, 0, 0, 1, STAGE_A(0, 1, t + 2), VM_NONE);
        QPHASE(1, 0, 1, 0, STAGE_B(1, 0, t + 3), VMW(10));
        QPHASE(1, 1, 0, 0, STAGE_B(1, 1, t + 3), VM_NONE);
        QPHASE(1, 1, 1, 0, STAGE_A(1, 0, t + 3), VMW(8));
    }
    // peeled last iteration (t=14): only A1(15) left to stage; exact waits
    QPHASE(0, 0, 0, 1, STAGE_A(1, 1, 15), VM_NONE);
    QPHASE(0, 0, 1, 0, VM_NONE, VMW(8));
    QPHASE(0, 1, 0, 0, VM_NONE, VM_NONE);
    QPHASE(0, 1, 1, 0, VM_NONE, VMW(2));
    QPHASE(1, 0, 0, 1, VM_NONE, VM_NONE);
    QPHASE(1, 0, 1, 0, VM_NONE, VMW(0));
    QPHASE(1, 1, 0, 0, VM_NONE, VM_NONE);
    QPHASE(1, 1, 1, 0, VM_NONE, VM_NONE);

#undef QPHASE
#undef STAGE_A
#undef STAGE_B
}

// ----------------------------------------------------- QKV GEMM + softmax
__global__ __launch_bounds__(512, 2)
void gemm_qkv(const bf16* __restrict__ A, const bf16* __restrict__ Bw,
              const float* __restrict__ bq, const float* __restrict__ bk,
              const float* __restrict__ bv,
              bf16* __restrict__ qb, bf16* __restrict__ kb, bf16* __restrict__ vb) {
    __shared__ bf16 ldsA[32768];
    __shared__ bf16 ldsB[32768];
    int tid = threadIdx.x;
    int bid = blockIdx.x;
    int swz = (bid & 7) * 192 + (bid >> 3);    // XCD-chunked, 1536 % 8 == 0
    int bn = swz % 12, bm = swz / 12;          // bn-fastest: A-panel L2 reuse

    floatx4 acc[8][4] = {};
    pipe256(A + (size_t)bm * 256 * CDIM, Bw + (size_t)bn * 256 * CDIM,
            ldsA, ldsB, tid, acc);

    int lane = tid & 63, wv = tid >> 6, quad = lane >> 4, l15 = lane & 15;
    int wm = wv >> 2, wn = wv & 3;
    int n_abs = bn * 256 + wn * 64;            // wave's 64 cols = one head blk
    bf16* dst; const float* biasp; int ncol0; bool smax;
    if (n_abs < 1024)      { dst = qb; biasp = bq; ncol0 = n_abs;        smax = true;  }
    else if (n_abs < 2048) { dst = kb; biasp = bk; ncol0 = n_abs - 1024; smax = true;  }
    else                   { dst = vb; biasp = bv; ncol0 = n_abs - 2048; smax = false; }
    float bias4[4];
    #pragma unroll
    for (int j = 0; j < 4; ++j) bias4[j] = biasp[ncol0 + j * 16 + l15];
    size_t row0 = (size_t)bm * 256 + wm * 64;

    #pragma unroll
    for (int i = 0; i < 8; ++i) {
        #pragma unroll
        for (int r = 0; r < 4; ++r) {
            float vals[4];
            #pragma unroll
            for (int j = 0; j < 4; ++j) vals[j] = acc[i][j][r] + bias4[j];
            if (smax) {
                float mx = fmaxf(fmaxf(vals[0], vals[1]), fmaxf(vals[2], vals[3]));
                #pragma unroll
                for (int d = 1; d < 16; d <<= 1) mx = fmaxf(mx, __shfl_xor(mx, d));
                float s = 0.f;
                #pragma unroll
                for (int j = 0; j < 4; ++j) { vals[j] = __expf(vals[j] - mx); s += vals[j]; }
                #pragma unroll
                for (int d = 1; d < 16; d <<= 1) s += __shfl_xor(s, d);
                float rinv = 1.0f / s;
                #pragma unroll
                for (int j = 0; j < 4; ++j) vals[j] *= rinv;
            }
            size_t row = row0 + ((i >> 2) * 128) + ((i & 3) * 16) + quad * 4 + r;
            #pragma unroll
            for (int j = 0; j < 4; ++j)
                dst[row * 1024 + ncol0 + j * 16 + l15] = __float2bfloat16(vals[j]);
        }
    }
}

// --------------------------------------------------- output GEMM (fp32 out)
__global__ __launch_bounds__(512, 2)
void gemm_out(const bf16* __restrict__ A, const bf16* __restrict__ Bw,
              const float* __restrict__ bp, float* __restrict__ outp) {
    __shared__ bf16 ldsA[32768];
    __shared__ bf16 ldsB[32768];
    int tid = threadIdx.x;
    int bid = blockIdx.x;
    int swz = (bid & 7) * 64 + (bid >> 3);     // 512 % 8 == 0
    int bn = swz & 3, bm = swz >> 2;

    floatx4 acc[8][4] = {};
    pipe256(A + (size_t)bm * 256 * CDIM, Bw + (size_t)bn * 256 * CDIM,
            ldsA, ldsB, tid, acc);

    int lane = tid & 63, wv = tid >> 6, quad = lane >> 4, l15 = lane & 15;
    int wm = wv >> 2, wn = wv & 3;
    int gcol0 = bn * 256 + wn * 64;
    float bias4[4];
    #pragma unroll
    for (int j = 0; j < 4; ++j) bias4[j] = bp[gcol0 + j * 16 + l15];
    size_t row0 = (size_t)bm * 256 + wm * 64;

    #pragma unroll
    for (int i = 0; i < 8; ++i) {
        #pragma unroll
        for (int r = 0; r < 4; ++r) {
            size_t row = row0 + ((i >> 2) * 128) + ((i & 3) * 16) + quad * 4 + r;
            #pragma unroll
            for (int j = 0; j < 4; ++j)
                __builtin_nontemporal_store(acc[i][j][r] + bias4[j],
                    &outp[row * 1024 + gcol0 + j * 16 + l15]);
        }
    }
}

// --------------------------------------------- context = k^T v  (+ k_sum)
// MFMA version: per 64-token subtile, stage k,v TRANSPOSED (kT[d][t]) into
// LDS with block-XOR swizzle: elem (d,t) at d*64 + (((t>>3)^(d&7)^(d>>3))<<3
// | (t&7)). Writes (vary d-coarse) and b128 frag reads (vary d-fine + t-blk)
// are both conflict-free. Then ctx[d][e] += MFMA(kT-row d, vT-row e).
__global__ __launch_bounds__(256)
void ctx_kernel(const bf16* __restrict__ kbuf, const bf16* __restrict__ vbuf,
                float* __restrict__ ctx, float* __restrict__ ksum) {
    int bid = blockIdx.x;
    int head = bid >> 4, chunk = bid & 15;
    int b = head >> 4, h = head & 15;
    size_t rowbase = (size_t)b * 8192 + (size_t)chunk * 512;
    int coff = h * 64;
    __shared__ unsigned short kT[4096];
    __shared__ unsigned short vT[4096];
    __shared__ float ksum_s[64];
    int tid = threadIdx.x, lane = tid & 63, wv = tid >> 6;
    int quad = lane >> 4, l15 = lane & 15;
    int c8 = tid & 7, trow = tid >> 3;          // trow 0..31; t = trow, trow+32
    if (tid < 64) ksum_s[tid] = 0.f;

    float kacc[8] = {0.f, 0.f, 0.f, 0.f, 0.f, 0.f, 0.f, 0.f};
    floatx4 acc4[4] = {};

    size_t g0 = (rowbase + trow) * 1024 + coff + c8 * 8;
    short8 pk0 = *(const short8*)(kbuf + g0);
    short8 pk1 = *(const short8*)(kbuf + g0 + 32 * 1024);
    short8 pv0 = *(const short8*)(vbuf + g0);
    short8 pv1 = *(const short8*)(vbuf + g0 + 32 * 1024);

    int tb0 = trow >> 3;                        // t-block of trow (0..3)
    for (int st = 0; st < 8; ++st) {
        __syncthreads();
        #pragma unroll
        for (int j = 0; j < 8; ++j) {
            int d = c8 * 8 + j;                 // d&7 == j, d>>3 == c8
            int base = d * 64 + (trow & 7);
            int sw0 = (tb0 ^ j ^ c8) << 3;
            int sw1 = ((tb0 + 4) ^ j ^ c8) << 3;
            unsigned short ku0 = (unsigned short)((short*)&pk0)[j];
            unsigned short ku1 = (unsigned short)((short*)&pk1)[j];
            kT[base + sw0] = ku0;
            kT[base + sw1] = ku1;
            vT[base + sw0] = (unsigned short)((short*)&pv0)[j];
            vT[base + sw1] = (unsigned short)((short*)&pv1)[j];
            kacc[j] += bfbits2f(ku0) + bfbits2f(ku1);
        }
        __syncthreads();
        if (st < 7) {
            size_t g = g0 + (size_t)(st + 1) * 64 * 1024;
            pk0 = *(const short8*)(kbuf + g);
            pk1 = *(const short8*)(kbuf + g + 32 * 1024);
            pv0 = *(const short8*)(vbuf + g);
            pv1 = *(const short8*)(vbuf + g + 32 * 1024);
        }
        #pragma unroll
        for (int ks = 0; ks < 2; ++ks) {
            int dA = wv * 16 + l15;
            int blkA = (ks * 4 + quad) ^ (dA & 7) ^ (dA >> 3);
            short8 aF = *(const short8*)&kT[dA * 64 + (blkA << 3)];
            #pragma unroll
            for (int n = 0; n < 4; ++n) {
                int eB = n * 16 + l15;
                int blkB = (ks * 4 + quad) ^ (eB & 7) ^ (eB >> 3);
                short8 bF = *(const short8*)&vT[eB * 64 + (blkB << 3)];
                acc4[n] = MFMA16(aF, bF, acc4[n]);
            }
        }
    }

    // ksum: reduce over lanes sharing c8 (strides 8,16,32), LDS-accumulate
    #pragma unroll
    for (int j = 0; j < 8; ++j) {
        float v = kacc[j];
        v += __shfl_xor(v, 8); v += __shfl_xor(v, 16); v += __shfl_xor(v, 32);
        if (lane < 8) atomicAdd(&ksum_s[lane * 8 + j], v);
    }
    float* cptr = ctx + (size_t)head * 4096;
    #pragma unroll
    for (int n = 0; n < 4; ++n)
        #pragma unroll
        for (int rr = 0; rr < 4; ++rr) {
            int d = wv * 16 + quad * 4 + rr;
            int e = n * 16 + l15;
            atomicAdd(&cptr[d * 64 + e], acc4[n][rr]);
        }
    __syncthreads();
    if (tid < 64) atomicAdd(&ksum[head * 64 + tid], ksum_s[tid]);
}

// --------------------------------- out_attn = q @ ctx * Dinv + q  (MFMA)
// R7: 2048 blocks; each handles 4 consecutive 64-token tiles of one head.
// ctx^T + ksum staged ONCE; q double-buffered in LDS with register prefetch
// of the next tile overlapping dinv+MFMA. Barriers: 2 per iteration
// (qs-write -> readers; dinv-write -> readers); buffer alternation gives two
// barriers between any qs read and its overwrite.
#define QS 72
__global__ __launch_bounds__(256)
void attn_kernel(const bf16* __restrict__ qbuf, const float* __restrict__ ctx,
                 const float* __restrict__ ksum, bf16* __restrict__ ab) {
    int bid = blockIdx.x;
    int head = bid >> 5, grp = bid & 31;
    int b = head >> 4, h = head & 15;
    int coff = h * 64;
    __shared__ bf16 qs[2][64 * QS];
    __shared__ bf16 cts[64 * QS];
    __shared__ float ksums[64];
    __shared__ float dinv[64];
    int tid = threadIdx.x, lane = tid & 63, wv = tid >> 6;
    int lrow = tid >> 2, lpart = tid & 3;
    int quad = lane >> 4, l15 = lane & 15;
    int trow0 = wv * 16;

    { // stage ctx transposed + cvt to bf16 (once per block)
        const float* cp = ctx + (size_t)head * 4096;
        #pragma unroll
        for (int it = 0; it < 4; ++it) {
            int fi = it * 256 + tid;
            int d = fi >> 4, e0 = (fi & 15) * 4;
            float4 f = ((const float4*)cp)[fi];
            cts[(e0 + 0) * QS + d] = __float2bfloat16(f.x);
            cts[(e0 + 1) * QS + d] = __float2bfloat16(f.y);
            cts[(e0 + 2) * QS + d] = __float2bfloat16(f.z);
            cts[(e0 + 3) * QS + d] = __float2bfloat16(f.w);
        }
    }
    if (tid < 64) ksums[tid] = ksum[head * 64 + tid];

    size_t row00 = (size_t)b * 8192 + (size_t)grp * 256;   // 4 tiles of 64
    size_t gq = (row00 + lrow) * 1024 + coff + lpart * 16;
    short8 qr0 = *(const short8*)(qbuf + gq);
    short8 qr1 = *(const short8*)(qbuf + gq + 8);

    #pragma unroll 1
    for (int it = 0; it < 4; ++it) {
        bf16* qsb = qs[it & 1];
        *(short8*)&qsb[lrow * QS + lpart * 16]     = qr0;
        *(short8*)&qsb[lrow * QS + lpart * 16 + 8] = qr1;
        __syncthreads();                       // qs/cts/ksums -> readers
        if (it < 3) {                          // prefetch next tile (in flight
            size_t g = gq + (size_t)(it + 1) * 64 * 1024;   // across dinv+MFMA)
            qr0 = *(const short8*)(qbuf + g);
            qr1 = *(const short8*)(qbuf + g + 8);
        }
        { // Dinv[t] = 1 / sum_d q[t,d]*ksum[d]
            int t = tid >> 2, dg = tid & 3;
            float p = 0.f;
            #pragma unroll
            for (int j = 0; j < 16; ++j)
                p = fmaf(__bfloat162float(qsb[t * QS + dg * 16 + j]), ksums[dg * 16 + j], p);
            p += __shfl_xor(p, 1);
            p += __shfl_xor(p, 2);
            if (dg == 0) dinv[t] = 1.0f / p;
        }
        __syncthreads();                       // dinv -> readers

        size_t row0 = row00 + (size_t)it * 64;
        short8 aF0 = *(const short8*)&qsb[(trow0 + l15) * QS + quad * 8];
        short8 aF1 = *(const short8*)&qsb[(trow0 + l15) * QS + 32 + quad * 8];
        floatx4 acc[4] = {};
        #pragma unroll
        for (int ni = 0; ni < 4; ++ni) {
            short8 b0 = *(const short8*)&cts[(ni * 16 + l15) * QS + quad * 8];
            short8 b1 = *(const short8*)&cts[(ni * 16 + l15) * QS + 32 + quad * 8];
            acc[ni] = MFMA16(aF0, b0, acc[ni]);
            acc[ni] = MFMA16(aF1, b1, acc[ni]);
        }
        float dv[4];
        #pragma unroll
        for (int r = 0; r < 4; ++r) dv[r] = dinv[trow0 + quad * 4 + r];
        #pragma unroll
        for (int ni = 0; ni < 4; ++ni) {
            #pragma unroll
            for (int r = 0; r < 4; ++r) {
                int row = trow0 + quad * 4 + r;
                int col = ni * 16 + l15;
                float val = acc[ni][r] * dv[r] + __bfloat162float(qsb[row * QS + col]);
                ab[(row0 + row) * 1024 + coff + col] = __float2bfloat16(val);
            }
        }
        // no trailing barrier: next iter writes the OTHER qs buffer; this
        // buffer's next overwrite is 2 barriers away (iter it+1's pair).
    }
}

// ------------------------------------------------------------------ launch
extern "C" void kernel_launch(void* const* d_in, const int* in_sizes, int n_in,
                              void* d_out, int out_size, void* d_ws, size_t ws_size,
                              hipStream_t stream) {
    const float* x  = (const float*)d_in[0];
    const float* Wq = (const float*)d_in[1];
    const float* bq = (const float*)d_in[2];
    const float* Wk = (const float*)d_in[3];
    const float* bk = (const float*)d_in[4];
    const float* Wv = (const float*)d_in[5];
    const float* bv = (const float*)d_in[6];
    const float* Wp = (const float*)d_in[7];
    const float* bp = (const float*)d_in[8];
    float* outp = (float*)d_out;

    char* ws = (char*)d_ws;
    bf16*  xb   = (bf16*)(ws);                       // 64 MB
    bf16*  Wb   = (bf16*)(ws + 67108864);            // 8 MB (Wq,Wk,Wv,Wp rows)
    bf16*  qb   = (bf16*)(ws + 75497472);            // 64 MB
    bf16*  kb   = (bf16*)(ws + 142606336);           // 64 MB
    bf16*  vb   = (bf16*)(ws + 209715200);           // 64 MB
    float* ctx  = (float*)(ws + 276824064);          // 1 MB
    float* ksum = (float*)(ws + 277872640);          // 16 KB
    bf16*  ab   = (bf16*)(ws);                       // aliases xb (dead by then)

    prep_kernel<<<4096, 256, 0, stream>>>(x, Wq, Wk, Wv, Wp, xb, Wb, ctx);
    gemm_qkv<<<1536, 512, 0, stream>>>(xb, Wb, bq, bk, bv, qb, kb, vb);
    ctx_kernel<<<1024, 256, 0, stream>>>(kb, vb, ctx, ksum);
    attn_kernel<<<2048, 256, 0, stream>>>(qb, ctx, ksum, ab);
    gemm_out<<<512, 512, 0, stream>>>(ab, Wb + (size_t)3072 * 1024, bp, outp);
}

// Round 6
// 630.562 us; speedup vs baseline: 1.1475x; 1.0154x over previous
//
#include <hip/hip_runtime.h>
#include <hip/hip_bf16.h>
#include <stdint.h>

// R8 = R7 with gemm_qkv split into 3 dispatches (q,k,v) of the identical
// pipe256 (epilogue dst/bias/smax parameterized). Zero expected perf delta;
// purpose: each qkv dispatch drops to ~92us so the top-5 profile rows expose
// the true cost of gemm_out / ctx / attn / prep (165us currently unaccounted).

#define BT    32768   // B*T
#define CDIM  1024

using bf16 = __hip_bfloat16;
typedef short  short8   __attribute__((ext_vector_type(8)));
typedef short  short4_t __attribute__((ext_vector_type(4)));
typedef unsigned short ushort4_t __attribute__((ext_vector_type(4)));
typedef float  floatx4  __attribute__((ext_vector_type(4)));

__device__ __forceinline__ float bfbits2f(unsigned short u) {
    union { unsigned int i; float f; } c; c.i = ((unsigned int)u) << 16; return c.f;
}

__device__ __forceinline__ void gld_lds16(const void* g, void* lds) {
    __builtin_amdgcn_global_load_lds(
        (const __attribute__((address_space(1))) uint32_t*)g,
        (__attribute__((address_space(3))) uint32_t*)lds,
        16, 0, 0);
}

// ------------------------------------- fp32 -> bf16 conversion + ctx zeroing
__global__ __launch_bounds__(256)
void prep_kernel(const float* __restrict__ x,
                 const float* __restrict__ Wq, const float* __restrict__ Wk,
                 const float* __restrict__ Wv, const float* __restrict__ Wp,
                 bf16* __restrict__ xb, bf16* __restrict__ Wb,
                 float* __restrict__ zp) {
    const int XF4 = (BT * CDIM) / 4;           // 8388608
    const int TOT = XF4 + 4 * 262144;          // 9437184 = 9 * 1048576
    int t0 = blockIdx.x * 256 + threadIdx.x;   // grid 4096*256 = 1048576
    if (t0 < 66560) {                          // zero ctx (1MB) + ksum (16KB)
        float4 z = {0.f, 0.f, 0.f, 0.f};
        ((float4*)zp)[t0] = z;
    }
    #pragma unroll 1
    for (int i = t0; i < TOT; i += 1048576) {
        const float* src; bf16* dst; int off;
        if (i < XF4) { src = x; dst = xb; off = i; }
        else {
            int i2 = i - XF4;
            int wi = i2 >> 18;                  // 262144 float4 per matrix
            off = i2 & 0x3FFFF;
            src = (wi == 0) ? Wq : (wi == 1) ? Wk : (wi == 2) ? Wv : Wp;
            dst = Wb + (size_t)wi * 1048576;
        }
        float4 f = ((const float4*)src)[off];
        union { bf16 h[4]; short4_t v; } u;
        u.h[0] = __float2bfloat16(f.x); u.h[1] = __float2bfloat16(f.y);
        u.h[2] = __float2bfloat16(f.z); u.h[3] = __float2bfloat16(f.w);
        *(short4_t*)(dst + (size_t)off * 4) = u.v;
    }
}

// =================== 256x256 / BK=64 8-phase GEMM pipeline (R3) ===========
// LDS tile layout (per A/B, per buf, per half): [128 rows][8 chunks of 8 bf16]
// with chunk' = chunk ^ (row&7). global_load_lds writes linearly; inverse
// swizzle applied to the per-lane GLOBAL address.

__device__ __forceinline__ short8 frag_ld(const bf16* hb, int r, int s4q) {
    return *(const short8*)(hb + r * 64 + (((s4q) ^ (r & 7)) << 3));
}

// stage one 128x64 half-tile: 2 x global_load_lds_dwordx4 per thread
__device__ __forceinline__ void stage_half(const bf16* g, bf16* l, int tid) {
    int ln = tid & 63, w = tid >> 6;
    int r = w * 8 + (ln >> 3);
    int c = ((ln & 7) ^ (ln >> 3)) << 3;        // pre-swizzled source chunk
    gld_lds16(g + (size_t)r * CDIM + c, l + w * 512);
    gld_lds16(g + (size_t)(r + 64) * CDIM + c, l + 4096 + w * 512);
}

#define MFMA16(a, b, c) __builtin_amdgcn_mfma_f32_16x16x32_bf16(a, b, c, 0, 0, 0)
#define VMW(n) asm volatile("s_waitcnt vmcnt(" #n ")" ::: "memory")
#define VM_NONE

__device__ __forceinline__ void pipe256(const bf16* __restrict__ Ab,
                                        const bf16* __restrict__ Bb,
                                        bf16* ldsA, bf16* ldsB,
                                        int tid, floatx4 acc[8][4]) {
    const int lane = tid & 63;
    const int wv = tid >> 6;
    const int quad = lane >> 4, l15 = lane & 15;
    const int wm = wv >> 2, wn = wv & 3;
    const int rA0 = wm * 64 + l15;              // + mm*32 + ii*16
    const int rB0 = (wn & 1) * 64 + l15;        // + j*16
    const bf16* ldsBh = ldsB + (wn >> 1) * 8192;  // wave's fixed B half
    short8 bfr[4][2];

#define STAGE_A(b, h, kt) stage_half(Ab + (size_t)((h) * 128) * CDIM + (kt) * 64, \
                                     ldsA + (b) * 16384 + (h) * 8192, tid)
#define STAGE_B(b, h, kt) stage_half(Bb + (size_t)((h) * 128) * CDIM + (kt) * 64, \
                                     ldsB + (b) * 16384 + (h) * 8192, tid)

#define QPHASE(BUF, QA, MM, LOADB, STG, VMC) do {                              \
    const bf16* aH_ = ldsA + (BUF) * 16384 + (QA) * 8192;                      \
    short8 a00_ = frag_ld(aH_, rA0 + (MM) * 32,      quad);                    \
    short8 a01_ = frag_ld(aH_, rA0 + (MM) * 32,      4 + quad);                \
    short8 a10_ = frag_ld(aH_, rA0 + (MM) * 32 + 16, quad);                    \
    short8 a11_ = frag_ld(aH_, rA0 + (MM) * 32 + 16, 4 + quad);                \
    if (LOADB) {                                                               \
        const bf16* bH_ = ldsBh + (BUF) * 16384;                               \
        _Pragma("unroll")                                                      \
        for (int j = 0; j < 4; ++j) {                                          \
            bfr[j][0] = frag_ld(bH_, rB0 + j * 16, quad);                      \
            bfr[j][1] = frag_ld(bH_, rB0 + j * 16, 4 + quad);                  \
        }                                                                      \
    }                                                                          \
    STG; VMC;                                                                  \
    __builtin_amdgcn_s_barrier();                                              \
    asm volatile("s_waitcnt lgkmcnt(0)" ::: "memory");                         \
    __builtin_amdgcn_s_setprio(1);                                             \
    _Pragma("unroll")                                                          \
    for (int j = 0; j < 4; ++j) {                                              \
        acc[(QA)*4+(MM)*2  ][j] = MFMA16(a00_, bfr[j][0], acc[(QA)*4+(MM)*2  ][j]); \
        acc[(QA)*4+(MM)*2  ][j] = MFMA16(a01_, bfr[j][1], acc[(QA)*4+(MM)*2  ][j]); \
        acc[(QA)*4+(MM)*2+1][j] = MFMA16(a10_, bfr[j][0], acc[(QA)*4+(MM)*2+1][j]); \
        acc[(QA)*4+(MM)*2+1][j] = MFMA16(a11_, bfr[j][1], acc[(QA)*4+(MM)*2+1][j]); \
    }                                                                          \
    __builtin_amdgcn_s_setprio(0);                                             \
    __builtin_amdgcn_s_barrier();                                              \
} while (0)

    // prologue: t0 fully + t1 {B0,B1,A0}; wait oldest 3 halves (t0 B0,B1,A0)
    STAGE_B(0, 0, 0); STAGE_B(0, 1, 0); STAGE_A(0, 0, 0); STAGE_A(0, 1, 0);
    STAGE_B(1, 0, 1); STAGE_B(1, 1, 1); STAGE_A(1, 0, 1);
    VMW(8);
    __builtin_amdgcn_s_barrier();

    #pragma unroll 1
    for (int i = 0; i < 7; ++i) {
        int t = 2 * i;
        QPHASE(0, 0, 0, 1, STAGE_A(1, 1, t + 1), VM_NONE);
        QPHASE(0, 0, 1, 0, STAGE_B(0, 0, t + 2), VMW(10));
        QPHASE(0, 1, 0, 0, STAGE_B(0, 1, t + 2), VM_NONE);
        QPHASE(0, 1, 1, 0, STAGE_A(0, 0, t + 2), VMW(8));
        QPHASE(1, 0, 0, 1, STAGE_A(0, 1, t + 2), VM_NONE);
        QPHASE(1, 0, 1, 0, STAGE_B(1, 0, t + 3), VMW(10));
        QPHASE(1, 1, 0, 0, STAGE_B(1, 1, t + 3), VM_NONE);
        QPHASE(1, 1, 1, 0, STAGE_A(1, 0, t + 3), VMW(8));
    }
    // peeled last iteration (t=14): only A1(15) left to stage; exact waits
    QPHASE(0, 0, 0, 1, STAGE_A(1, 1, 15), VM_NONE);
    QPHASE(0, 0, 1, 0, VM_NONE, VMW(8));
    QPHASE(0, 1, 0, 0, VM_NONE, VM_NONE);
    QPHASE(0, 1, 1, 0, VM_NONE, VMW(2));
    QPHASE(1, 0, 0, 1, VM_NONE, VM_NONE);
    QPHASE(1, 0, 1, 0, VM_NONE, VMW(0));
    QPHASE(1, 1, 0, 0, VM_NONE, VM_NONE);
    QPHASE(1, 1, 1, 0, VM_NONE, VM_NONE);

#undef QPHASE
#undef STAGE_A
#undef STAGE_B
}

// ------------------------- one of the QKV GEMMs (+ optional softmax) ------
// grid 512: bm 128 x bn 4; same per-block work as the fused R7 version.
__global__ __launch_bounds__(512, 2)
void gemm_qkv1(const bf16* __restrict__ A, const bf16* __restrict__ Bw,
               const float* __restrict__ bias, bf16* __restrict__ dst,
               int smax) {
    __shared__ bf16 ldsA[32768];
    __shared__ bf16 ldsB[32768];
    int tid = threadIdx.x;
    int bid = blockIdx.x;
    int swz = (bid & 7) * 64 + (bid >> 3);     // XCD-chunked, 512 % 8 == 0
    int bn = swz & 3, bm = swz >> 2;

    floatx4 acc[8][4] = {};
    pipe256(A + (size_t)bm * 256 * CDIM, Bw + (size_t)bn * 256 * CDIM,
            ldsA, ldsB, tid, acc);

    int lane = tid & 63, wv = tid >> 6, quad = lane >> 4, l15 = lane & 15;
    int wm = wv >> 2, wn = wv & 3;
    int ncol0 = bn * 256 + wn * 64;            // wave's 64 cols = one head
    float bias4[4];
    #pragma unroll
    for (int j = 0; j < 4; ++j) bias4[j] = bias[ncol0 + j * 16 + l15];
    size_t row0 = (size_t)bm * 256 + wm * 64;

    #pragma unroll
    for (int i = 0; i < 8; ++i) {
        #pragma unroll
        for (int r = 0; r < 4; ++r) {
            float vals[4];
            #pragma unroll
            for (int j = 0; j < 4; ++j) vals[j] = acc[i][j][r] + bias4[j];
            if (smax) {
                float mx = fmaxf(fmaxf(vals[0], vals[1]), fmaxf(vals[2], vals[3]));
                #pragma unroll
                for (int d = 1; d < 16; d <<= 1) mx = fmaxf(mx, __shfl_xor(mx, d));
                float s = 0.f;
                #pragma unroll
                for (int j = 0; j < 4; ++j) { vals[j] = __expf(vals[j] - mx); s += vals[j]; }
                #pragma unroll
                for (int d = 1; d < 16; d <<= 1) s += __shfl_xor(s, d);
                float rinv = 1.0f / s;
                #pragma unroll
                for (int j = 0; j < 4; ++j) vals[j] *= rinv;
            }
            size_t row = row0 + ((i >> 2) * 128) + ((i & 3) * 16) + quad * 4 + r;
            #pragma unroll
            for (int j = 0; j < 4; ++j)
                dst[row * 1024 + ncol0 + j * 16 + l15] = __float2bfloat16(vals[j]);
        }
    }
}

// --------------------------------------------------- output GEMM (fp32 out)
__global__ __launch_bounds__(512, 2)
void gemm_out(const bf16* __restrict__ A, const bf16* __restrict__ Bw,
              const float* __restrict__ bp, float* __restrict__ outp) {
    __shared__ bf16 ldsA[32768];
    __shared__ bf16 ldsB[32768];
    int tid = threadIdx.x;
    int bid = blockIdx.x;
    int swz = (bid & 7) * 64 + (bid >> 3);     // 512 % 8 == 0
    int bn = swz & 3, bm = swz >> 2;

    floatx4 acc[8][4] = {};
    pipe256(A + (size_t)bm * 256 * CDIM, Bw + (size_t)bn * 256 * CDIM,
            ldsA, ldsB, tid, acc);

    int lane = tid & 63, wv = tid >> 6, quad = lane >> 4, l15 = lane & 15;
    int wm = wv >> 2, wn = wv & 3;
    int gcol0 = bn * 256 + wn * 64;
    float bias4[4];
    #pragma unroll
    for (int j = 0; j < 4; ++j) bias4[j] = bp[gcol0 + j * 16 + l15];
    size_t row0 = (size_t)bm * 256 + wm * 64;

    #pragma unroll
    for (int i = 0; i < 8; ++i) {
        #pragma unroll
        for (int r = 0; r < 4; ++r) {
            size_t row = row0 + ((i >> 2) * 128) + ((i & 3) * 16) + quad * 4 + r;
            #pragma unroll
            for (int j = 0; j < 4; ++j)
                __builtin_nontemporal_store(acc[i][j][r] + bias4[j],
                    &outp[row * 1024 + gcol0 + j * 16 + l15]);
        }
    }
}

// --------------------------------------------- context = k^T v  (+ k_sum)
// MFMA version: per 64-token subtile, stage k,v TRANSPOSED (kT[d][t]) into
// LDS with block-XOR swizzle: elem (d,t) at d*64 + (((t>>3)^(d&7)^(d>>3))<<3
// | (t&7)). Writes (vary d-coarse) and b128 frag reads (vary d-fine + t-blk)
// are both conflict-free. Then ctx[d][e] += MFMA(kT-row d, vT-row e).
__global__ __launch_bounds__(256)
void ctx_kernel(const bf16* __restrict__ kbuf, const bf16* __restrict__ vbuf,
                float* __restrict__ ctx, float* __restrict__ ksum) {
    int bid = blockIdx.x;
    int head = bid >> 4, chunk = bid & 15;
    int b = head >> 4, h = head & 15;
    size_t rowbase = (size_t)b * 8192 + (size_t)chunk * 512;
    int coff = h * 64;
    __shared__ unsigned short kT[4096];
    __shared__ unsigned short vT[4096];
    __shared__ float ksum_s[64];
    int tid = threadIdx.x, lane = tid & 63, wv = tid >> 6;
    int quad = lane >> 4, l15 = lane & 15;
    int c8 = tid & 7, trow = tid >> 3;          // trow 0..31; t = trow, trow+32
    if (tid < 64) ksum_s[tid] = 0.f;

    float kacc[8] = {0.f, 0.f, 0.f, 0.f, 0.f, 0.f, 0.f, 0.f};
    floatx4 acc4[4] = {};

    size_t g0 = (rowbase + trow) * 1024 + coff + c8 * 8;
    short8 pk0 = *(const short8*)(kbuf + g0);
    short8 pk1 = *(const short8*)(kbuf + g0 + 32 * 1024);
    short8 pv0 = *(const short8*)(vbuf + g0);
    short8 pv1 = *(const short8*)(vbuf + g0 + 32 * 1024);

    int tb0 = trow >> 3;                        // t-block of trow (0..3)
    for (int st = 0; st < 8; ++st) {
        __syncthreads();
        #pragma unroll
        for (int j = 0; j < 8; ++j) {
            int d = c8 * 8 + j;                 // d&7 == j, d>>3 == c8
            int base = d * 64 + (trow & 7);
            int sw0 = (tb0 ^ j ^ c8) << 3;
            int sw1 = ((tb0 + 4) ^ j ^ c8) << 3;
            unsigned short ku0 = (unsigned short)((short*)&pk0)[j];
            unsigned short ku1 = (unsigned short)((short*)&pk1)[j];
            kT[base + sw0] = ku0;
            kT[base + sw1] = ku1;
            vT[base + sw0] = (unsigned short)((short*)&pv0)[j];
            vT[base + sw1] = (unsigned short)((short*)&pv1)[j];
            kacc[j] += bfbits2f(ku0) + bfbits2f(ku1);
        }
        __syncthreads();
        if (st < 7) {
            size_t g = g0 + (size_t)(st + 1) * 64 * 1024;
            pk0 = *(const short8*)(kbuf + g);
            pk1 = *(const short8*)(kbuf + g + 32 * 1024);
            pv0 = *(const short8*)(vbuf + g);
            pv1 = *(const short8*)(vbuf + g + 32 * 1024);
        }
        #pragma unroll
        for (int ks = 0; ks < 2; ++ks) {
            int dA = wv * 16 + l15;
            int blkA = (ks * 4 + quad) ^ (dA & 7) ^ (dA >> 3);
            short8 aF = *(const short8*)&kT[dA * 64 + (blkA << 3)];
            #pragma unroll
            for (int n = 0; n < 4; ++n) {
                int eB = n * 16 + l15;
                int blkB = (ks * 4 + quad) ^ (eB & 7) ^ (eB >> 3);
                short8 bF = *(const short8*)&vT[eB * 64 + (blkB << 3)];
                acc4[n] = MFMA16(aF, bF, acc4[n]);
            }
        }
    }

    // ksum: reduce over lanes sharing c8 (strides 8,16,32), LDS-accumulate
    #pragma unroll
    for (int j = 0; j < 8; ++j) {
        float v = kacc[j];
        v += __shfl_xor(v, 8); v += __shfl_xor(v, 16); v += __shfl_xor(v, 32);
        if (lane < 8) atomicAdd(&ksum_s[lane * 8 + j], v);
    }
    float* cptr = ctx + (size_t)head * 4096;
    #pragma unroll
    for (int n = 0; n < 4; ++n)
        #pragma unroll
        for (int rr = 0; rr < 4; ++rr) {
            int d = wv * 16 + quad * 4 + rr;
            int e = n * 16 + l15;
            atomicAdd(&cptr[d * 64 + e], acc4[n][rr]);
        }
    __syncthreads();
    if (tid < 64) atomicAdd(&ksum[head * 64 + tid], ksum_s[tid]);
}

// --------------------------------- out_attn = q @ ctx * Dinv + q  (MFMA)
// 2048 blocks; each handles 4 consecutive 64-token tiles of one head.
// ctx^T + ksum staged ONCE; q double-buffered in LDS with register prefetch.
#define QS 72
__global__ __launch_bounds__(256)
void attn_kernel(const bf16* __restrict__ qbuf, const float* __restrict__ ctx,
                 const float* __restrict__ ksum, bf16* __restrict__ ab) {
    int bid = blockIdx.x;
    int head = bid >> 5, grp = bid & 31;
    int b = head >> 4, h = head & 15;
    int coff = h * 64;
    __shared__ bf16 qs[2][64 * QS];
    __shared__ bf16 cts[64 * QS];
    __shared__ float ksums[64];
    __shared__ float dinv[64];
    int tid = threadIdx.x, lane = tid & 63, wv = tid >> 6;
    int lrow = tid >> 2, lpart = tid & 3;
    int quad = lane >> 4, l15 = lane & 15;
    int trow0 = wv * 16;

    { // stage ctx transposed + cvt to bf16 (once per block)
        const float* cp = ctx + (size_t)head * 4096;
        #pragma unroll
        for (int it = 0; it < 4; ++it) {
            int fi = it * 256 + tid;
            int d = fi >> 4, e0 = (fi & 15) * 4;
            float4 f = ((const float4*)cp)[fi];
            cts[(e0 + 0) * QS + d] = __float2bfloat16(f.x);
            cts[(e0 + 1) * QS + d] = __float2bfloat16(f.y);
            cts[(e0 + 2) * QS + d] = __float2bfloat16(f.z);
            cts[(e0 + 3) * QS + d] = __float2bfloat16(f.w);
        }
    }
    if (tid < 64) ksums[tid] = ksum[head * 64 + tid];

    size_t row00 = (size_t)b * 8192 + (size_t)grp * 256;   // 4 tiles of 64
    size_t gq = (row00 + lrow) * 1024 + coff + lpart * 16;
    short8 qr0 = *(const short8*)(qbuf + gq);
    short8 qr1 = *(const short8*)(qbuf + gq + 8);

    #pragma unroll 1
    for (int it = 0; it < 4; ++it) {
        bf16* qsb = qs[it & 1];
        *(short8*)&qsb[lrow * QS + lpart * 16]     = qr0;
        *(short8*)&qsb[lrow * QS + lpart * 16 + 8] = qr1;
        __syncthreads();                       // qs/cts/ksums -> readers
        if (it < 3) {                          // prefetch next tile
            size_t g = gq + (size_t)(it + 1) * 64 * 1024;
            qr0 = *(const short8*)(qbuf + g);
            qr1 = *(const short8*)(qbuf + g + 8);
        }
        { // Dinv[t] = 1 / sum_d q[t,d]*ksum[d]
            int t = tid >> 2, dg = tid & 3;
            float p = 0.f;
            #pragma unroll
            for (int j = 0; j < 16; ++j)
                p = fmaf(__bfloat162float(qsb[t * QS + dg * 16 + j]), ksums[dg * 16 + j], p);
            p += __shfl_xor(p, 1);
            p += __shfl_xor(p, 2);
            if (dg == 0) dinv[t] = 1.0f / p;
        }
        __syncthreads();                       // dinv -> readers

        size_t row0 = row00 + (size_t)it * 64;
        short8 aF0 = *(const short8*)&qsb[(trow0 + l15) * QS + quad * 8];
        short8 aF1 = *(const short8*)&qsb[(trow0 + l15) * QS + 32 + quad * 8];
        floatx4 acc[4] = {};
        #pragma unroll
        for (int ni = 0; ni < 4; ++ni) {
            short8 b0 = *(const short8*)&cts[(ni * 16 + l15) * QS + quad * 8];
            short8 b1 = *(const short8*)&cts[(ni * 16 + l15) * QS + 32 + quad * 8];
            acc[ni] = MFMA16(aF0, b0, acc[ni]);
            acc[ni] = MFMA16(aF1, b1, acc[ni]);
        }
        float dv[4];
        #pragma unroll
        for (int r = 0; r < 4; ++r) dv[r] = dinv[trow0 + quad * 4 + r];
        #pragma unroll
        for (int ni = 0; ni < 4; ++ni) {
            #pragma unroll
            for (int r = 0; r < 4; ++r) {
                int row = trow0 + quad * 4 + r;
                int col = ni * 16 + l15;
                float val = acc[ni][r] * dv[r] + __bfloat162float(qsb[row * QS + col]);
                ab[(row0 + row) * 1024 + coff + col] = __float2bfloat16(val);
            }
        }
        // no trailing barrier: next iter writes the OTHER qs buffer; this
        // buffer's next overwrite is 2 barriers away (iter it+1's pair).
    }
}

// ------------------------------------------------------------------ launch
extern "C" void kernel_launch(void* const* d_in, const int* in_sizes, int n_in,
                              void* d_out, int out_size, void* d_ws, size_t ws_size,
                              hipStream_t stream) {
    const float* x  = (const float*)d_in[0];
    const float* Wq = (const float*)d_in[1];
    const float* bq = (const float*)d_in[2];
    const float* Wk = (const float*)d_in[3];
    const float* bk = (const float*)d_in[4];
    const float* Wv = (const float*)d_in[5];
    const float* bv = (const float*)d_in[6];
    const float* Wp = (const float*)d_in[7];
    const float* bp = (const float*)d_in[8];
    float* outp = (float*)d_out;

    char* ws = (char*)d_ws;
    bf16*  xb   = (bf16*)(ws);                       // 64 MB
    bf16*  Wb   = (bf16*)(ws + 67108864);            // 8 MB (Wq,Wk,Wv,Wp rows)
    bf16*  qb   = (bf16*)(ws + 75497472);            // 64 MB
    bf16*  kb   = (bf16*)(ws + 142606336);           // 64 MB
    bf16*  vb   = (bf16*)(ws + 209715200);           // 64 MB
    float* ctx  = (float*)(ws + 276824064);          // 1 MB
    float* ksum = (float*)(ws + 277872640);          // 16 KB
    bf16*  ab   = (bf16*)(ws);                       // aliases xb (dead by then)

    prep_kernel<<<4096, 256, 0, stream>>>(x, Wq, Wk, Wv, Wp, xb, Wb, ctx);
    gemm_qkv1<<<512, 512, 0, stream>>>(xb, Wb,                          bq, qb, 1);
    gemm_qkv1<<<512, 512, 0, stream>>>(xb, Wb + (size_t)1024 * 1024,    bk, kb, 1);
    gemm_qkv1<<<512, 512, 0, stream>>>(xb, Wb + (size_t)2048 * 1024,    bv, vb, 0);
    ctx_kernel<<<1024, 256, 0, stream>>>(kb, vb, ctx, ksum);
    attn_kernel<<<2048, 256, 0, stream>>>(qb, ctx, ksum, ab);
    gemm_out<<<512, 512, 0, stream>>>(ab, Wb + (size_t)3072 * 1024, bp, outp);
}